// Round 2
// baseline (102.622 us; speedup 1.0000x reference)
//
#include <hip/hip_runtime.h>

#define N_ROWS 8192LL
#define N_COLS 10000LL

// out[0] = loss_m.sum()/n, out[1] = loss_inter.sum()/n
// S_all  = sum over ALL entries of max(x+25, 0)
// per-target: plus = max(x_t+25,0) (wrongly counted in S_all), hinge = max(50-x_t,0)
// out1 = (S_all - sum plus)/n ; out0 = out1 + (sum hinge)/n

__global__ void __launch_bounds__(256) hinge_fused(const float4* __restrict__ in4,
                                                   const float* __restrict__ in,
                                                   const int* __restrict__ tgt,
                                                   float* __restrict__ out) {
    const long long n4 = N_ROWS * N_COLS / 4;          // 20,480,000
    const long long stride = (long long)gridDim.x * blockDim.x;
    long long i = (long long)blockIdx.x * blockDim.x + threadIdx.x;
    const long long gid = i;

    float acc = 0.0f;
    // 2x-unrolled grid-stride sweep: two independent 16B loads in flight
    for (; i + stride < n4; i += 2 * stride) {
        float4 a = in4[i];
        float4 b = in4[i + stride];
        acc += fmaxf(a.x + 25.0f, 0.0f) + fmaxf(a.y + 25.0f, 0.0f)
             + fmaxf(a.z + 25.0f, 0.0f) + fmaxf(a.w + 25.0f, 0.0f);
        acc += fmaxf(b.x + 25.0f, 0.0f) + fmaxf(b.y + 25.0f, 0.0f)
             + fmaxf(b.z + 25.0f, 0.0f) + fmaxf(b.w + 25.0f, 0.0f);
    }
    if (i < n4) {
        float4 a = in4[i];
        acc += fmaxf(a.x + 25.0f, 0.0f) + fmaxf(a.y + 25.0f, 0.0f)
             + fmaxf(a.z + 25.0f, 0.0f) + fmaxf(a.w + 25.0f, 0.0f);
    }

    // per-thread deltas to out0/out1; both include the sweep partial
    float d0 = acc, d1 = acc;
    if (gid < N_ROWS) {
        int t = tgt[gid];
        float x = in[gid * N_COLS + (long long)t];
        float plus  = fmaxf(x + 25.0f, 0.0f);
        float hinge = fmaxf(50.0f - x, 0.0f);
        d0 += hinge - plus;
        d1 += -plus;
    }

    // wave-64 butterfly-free shuffle reduce
    #pragma unroll
    for (int off = 32; off > 0; off >>= 1) {
        d0 += __shfl_down(d0, off, 64);
        d1 += __shfl_down(d1, off, 64);
    }
    __shared__ float s0[4], s1[4];
    const int lane = threadIdx.x & 63;
    const int wid  = threadIdx.x >> 6;
    if (lane == 0) { s0[wid] = d0; s1[wid] = d1; }
    __syncthreads();
    if (threadIdx.x == 0) {
        const float inv_n = 1.0f / (float)N_ROWS;
        atomicAdd(&out[0], (s0[0] + s0[1] + s0[2] + s0[3]) * inv_n);
        atomicAdd(&out[1], (s1[0] + s1[1] + s1[2] + s1[3]) * inv_n);
    }
}

extern "C" void kernel_launch(void* const* d_in, const int* in_sizes, int n_in,
                              void* d_out, int out_size, void* d_ws, size_t ws_size,
                              hipStream_t stream) {
    const float* inputs = (const float*)d_in[0];
    const int* targets = (const int*)d_in[1];
    float* out = (float*)d_out;

    hipMemsetAsync(out, 0, 2 * sizeof(float), stream);   // zero the 2 accumulators

    const int block = 256;
    const int grid = 2048;   // 256 CU × 8 blocks/CU; grid-stride covers 20.48M float4
    hinge_fused<<<grid, block, 0, stream>>>((const float4*)inputs, inputs, targets, out);
}

// Round 3
// 56.513 us; speedup vs baseline: 1.8159x; 1.8159x over previous
//
#include <hip/hip_runtime.h>

#define N_ROWS 8192LL
#define N_COLS 10000LL
#define GRID_BLKS 2048

// out[0] = loss_m.sum()/n, out[1] = loss_inter.sum()/n
// S_all  = sum over ALL entries of max(x+25, 0)
// per-target: plus = max(x_t+25,0) (wrongly counted in S_all), hinge = max(50-x_t,0)
// out1 = (S_all - sum plus)/n ; out0 = out1 + (sum hinge)/n

__global__ void __launch_bounds__(256) hinge_partials(const float4* __restrict__ in4,
                                                      const float* __restrict__ in,
                                                      const int* __restrict__ tgt,
                                                      float2* __restrict__ ws) {
    const long long n4 = N_ROWS * N_COLS / 4;          // 20,480,000
    const long long stride = (long long)GRID_BLKS * 256;
    const long long gid = (long long)blockIdx.x * blockDim.x + threadIdx.x;

    float acc = 0.0f;
    for (long long i = gid; i < n4; i += stride) {
        float4 v = in4[i];
        acc += fmaxf(v.x + 25.0f, 0.0f) + fmaxf(v.y + 25.0f, 0.0f)
             + fmaxf(v.z + 25.0f, 0.0f) + fmaxf(v.w + 25.0f, 0.0f);
    }

    // fold the 8192 target-column corrections into the first 8192 threads
    float d0 = acc, d1 = acc;
    if (gid < N_ROWS) {
        int t = tgt[gid];
        float x = in[gid * N_COLS + (long long)t];
        float plus  = fmaxf(x + 25.0f, 0.0f);
        float hinge = fmaxf(50.0f - x, 0.0f);
        d0 += hinge - plus;
        d1 -= plus;
    }

    #pragma unroll
    for (int off = 32; off > 0; off >>= 1) {
        d0 += __shfl_down(d0, off, 64);
        d1 += __shfl_down(d1, off, 64);
    }
    __shared__ float s0[4], s1[4];
    const int lane = threadIdx.x & 63;
    const int wid  = threadIdx.x >> 6;
    if (lane == 0) { s0[wid] = d0; s1[wid] = d1; }
    __syncthreads();
    if (threadIdx.x == 0) {
        // contention-free per-block partial store
        ws[blockIdx.x] = make_float2(s0[0] + s0[1] + s0[2] + s0[3],
                                     s1[0] + s1[1] + s1[2] + s1[3]);
    }
}

__global__ void __launch_bounds__(1024) hinge_reduce(const float2* __restrict__ ws,
                                                     float* __restrict__ out) {
    // 2048 float2 partials; 1024 threads, 2 each
    float2 a = ws[threadIdx.x];
    float2 b = ws[threadIdx.x + 1024];
    float d0 = a.x + b.x;
    float d1 = a.y + b.y;
    #pragma unroll
    for (int off = 32; off > 0; off >>= 1) {
        d0 += __shfl_down(d0, off, 64);
        d1 += __shfl_down(d1, off, 64);
    }
    __shared__ float s0[16], s1[16];
    const int lane = threadIdx.x & 63;
    const int wid  = threadIdx.x >> 6;
    if (lane == 0) { s0[wid] = d0; s1[wid] = d1; }
    __syncthreads();
    if (threadIdx.x == 0) {
        float t0 = 0.0f, t1 = 0.0f;
        #pragma unroll
        for (int k = 0; k < 16; ++k) { t0 += s0[k]; t1 += s1[k]; }
        const float inv_n = 1.0f / (float)N_ROWS;
        out[0] = t0 * inv_n;   // plain overwrite — no memset node needed
        out[1] = t1 * inv_n;
    }
}

extern "C" void kernel_launch(void* const* d_in, const int* in_sizes, int n_in,
                              void* d_out, int out_size, void* d_ws, size_t ws_size,
                              hipStream_t stream) {
    const float* inputs = (const float*)d_in[0];
    const int* targets = (const int*)d_in[1];
    float* out = (float*)d_out;
    float2* ws = (float2*)d_ws;   // needs 2048 * 8 = 16 KB scratch

    hinge_partials<<<GRID_BLKS, 256, 0, stream>>>((const float4*)inputs, inputs, targets, ws);
    hinge_reduce<<<1, 1024, 0, stream>>>(ws, out);
}